// Round 6
// baseline (135.292 us; speedup 1.0000x reference)
//
#include <hip/hip_runtime.h>

#define DIM 128

typedef __attribute__((ext_vector_type(8))) short bf16x8;
typedef __attribute__((ext_vector_type(4))) float f32x4;
typedef __attribute__((ext_vector_type(4))) unsigned int u32x4;

static __device__ __forceinline__ unsigned short f2bf_rne(float f) {
    union { float f; unsigned int i; } c; c.f = f;
    unsigned int u = c.i;
    return (unsigned short)((u + 0x7fffu + ((u >> 16) & 1u)) >> 16);
}
static __device__ __forceinline__ float bf2f(unsigned short u) {
    union { unsigned int i; float f; } c; c.i = ((unsigned int)u) << 16;
    return c.f;
}
static __device__ __forceinline__ unsigned int fbits(float f) {
    union { float f; unsigned int i; } c; c.f = f; return c.i;
}
static __device__ __forceinline__ unsigned int pack_bf16_rne(float lo, float hi) {
    unsigned int ul = fbits(lo), uh = fbits(hi);
    unsigned int tl = ul + 0x7fffu + ((ul >> 16) & 1u);
    unsigned int th = uh + 0x7fffu + ((uh >> 16) & 1u);
    return __builtin_amdgcn_perm(th, tl, 0x07060302u);
}

struct Frags {
    bf16x8 w1h0, w1l0, w1h1, w1l1, w2h, w2l;
    f32x4 b1v, b2v;
};

// A = W1^T (hi/lo bf16 split), A2 = W2 embed (hi/lo). W1 k-row order:
// [own 0..7 | x-1 | x+1 | y-1 | y+1 | z-1 | z+1] -> block0 quads {own,x-1,x+1,y-1},
// block1 quads {y+1,z-1,z+1,pad(zero weights)}.
static __device__ __forceinline__ void build_frags(
    const float* W1, const float* b1, const float* W2, const float* b2,
    int col, int quad, Frags& F)
{
#pragma unroll
    for (int j = 0; j < 8; ++j) {
        int k0 = quad * 8 + j;
        float w = W1[k0 * 16 + col];
        unsigned short hi = f2bf_rne(w);
        F.w1h0[j] = (short)hi;
        F.w1l0[j] = (short)f2bf_rne(w - bf2f(hi));

        int k1 = 32 + quad * 8 + j;
        float wv = (k1 < 56) ? W1[k1 * 16 + col] : 0.0f;
        hi = f2bf_rne(wv);
        F.w1h1[j] = (short)hi;
        F.w1l1[j] = (short)f2bf_rne(wv - bf2f(hi));

        float w2 = (j < 4 && col < 8) ? W2[(quad * 4 + j) * 8 + col] : 0.0f;
        hi = f2bf_rne(w2);
        F.w2h[j] = (short)hi;
        F.w2l[j] = (short)f2bf_rne(w2 - bf2f(hi));
    }
#pragma unroll
    for (int r = 0; r < 4; ++r) {
        F.b1v[r] = b1[quad * 4 + r];
        F.b2v[r] = (quad < 2) ? b2[quad * 4 + r] : 0.0f;
    }
}

__global__ __launch_bounds__(64) void setup_kernel(
    const float* __restrict__ W1, const float* __restrict__ b1,
    const float* __restrict__ W2, const float* __restrict__ b2,
    u32x4* __restrict__ ws)
{
    const int lane = threadIdx.x;
    Frags F;
    build_frags(W1, b1, W2, b2, lane & 15, lane >> 4, F);
    union { bf16x8 v; u32x4 u; } c;
    c.v = F.w1h0; ws[0 * 64 + lane] = c.u;
    c.v = F.w1l0; ws[1 * 64 + lane] = c.u;
    c.v = F.w1h1; ws[2 * 64 + lane] = c.u;
    c.v = F.w1l1; ws[3 * 64 + lane] = c.u;
    c.v = F.w2h;  ws[4 * 64 + lane] = c.u;
    c.v = F.w2l;  ws[5 * 64 + lane] = c.u;
    union { f32x4 v; u32x4 u; } b;
    b.v = F.b1v; ws[6 * 64 + lane] = b.u;
    b.v = F.b2v; ws[7 * 64 + lane] = b.u;
}

// Block (4 waves) covers x=0..127, y=y0..y0+3, one z.
// Stage 14 rows to LDS as bf16 (perm during staging): 28 tasks of one half-row
// (64 cells) each, 7 per wave, all global loads issued before LDS writes.
// LDS slots: 0..5 = (y0-1..y0+4, z); 6..9 = (y0..y0+3, z-1); 11..14 = (y0..y0+3, z+1)
// (slot 10 is a hole so pB slot deltas {4,9,5} avoid bank-phase collision).
// Row stride 2064 B = 129*16 -> bank-group rotation of 1 per slot.
#define SLOT_STRIDE 2064
template<bool USE_WS>
__global__ __launch_bounds__(256, 4) void lattice_kernel(
    const float* __restrict__ states,
    const float* __restrict__ W1, const float* __restrict__ b1,
    const float* __restrict__ W2, const float* __restrict__ b2,
    float* __restrict__ out, const u32x4* __restrict__ ws)
{
    __shared__ __align__(16) unsigned char lds[15 * SLOT_STRIDE];   // 30960 B

    const int tid  = threadIdx.x;
    const int lane = tid & 63;
    const int wave = tid >> 6;
    const int col  = lane & 15;
    const int quad = lane >> 4;

    Frags F;
    if (USE_WS) {
        union { u32x4 u; bf16x8 v; } c;
        c.u = ws[0 * 64 + lane]; F.w1h0 = c.v;
        c.u = ws[1 * 64 + lane]; F.w1l0 = c.v;
        c.u = ws[2 * 64 + lane]; F.w1h1 = c.v;
        c.u = ws[3 * 64 + lane]; F.w1l1 = c.v;
        c.u = ws[4 * 64 + lane]; F.w2h  = c.v;
        c.u = ws[5 * 64 + lane]; F.w2l  = c.v;
        union { u32x4 u; f32x4 v; } b;
        b.u = ws[6 * 64 + lane]; F.b1v = b.v;
        b.u = ws[7 * 64 + lane]; F.b2v = b.v;
    } else {
        build_frags(W1, b1, W2, b2, col, quad, F);
    }

    // z-slab XCD swizzle: blockIdx&7 -> 16-z-plane slab
    const int bI   = blockIdx.x;
    const int slab = bI & 7;
    const int inr  = bI >> 3;            // 0..511
    const int z    = slab * 16 + (inr >> 5);
    const int y0   = (inr & 31) << 2;

    // ---- stage: 28 tasks (slot, half), 7 per wave; loads first (MLP), then LDS writes ----
    f32x4 ga[7], gb[7];
    int   laddr[7];
#pragma unroll
    for (int i = 0; i < 7; ++i) {
        const int tk   = wave * 7 + i;          // 0..27
        const int slot = (tk < 20) ? (tk >> 1) : 11 + ((tk - 20) >> 1);
        const int half = tk & 1;
        int yr, zr;
        if (slot < 6)       { yr = (y0 - 1 + slot) & 127; zr = z; }
        else if (slot < 10) { yr = y0 + (slot - 6);       zr = (z - 1) & 127; }
        else                { yr = y0 + (slot - 11);      zr = (z + 1) & 127; }
        const int c = half * 64 + lane;         // cell in row, 0..127
        const float* g = states + ((size_t)(zr * 16384 + yr * 128 + c) << 3);
        ga[i] = *(const f32x4*)g;
        gb[i] = *(const f32x4*)(g + 4);
        laddr[i] = slot * SLOT_STRIDE + c * 16;
    }
#pragma unroll
    for (int i = 0; i < 7; ++i) {
        u32x4 p;
        p[0] = __builtin_amdgcn_perm(fbits(ga[i][1]), fbits(ga[i][0]), 0x07060302u);
        p[1] = __builtin_amdgcn_perm(fbits(ga[i][3]), fbits(ga[i][2]), 0x07060302u);
        p[2] = __builtin_amdgcn_perm(fbits(gb[i][1]), fbits(gb[i][0]), 0x07060302u);
        p[3] = __builtin_amdgcn_perm(fbits(gb[i][3]), fbits(gb[i][2]), 0x07060302u);
        *(u32x4*)(lds + laddr[i]) = p;
    }
    __syncthreads();

    // ---- per-lane LDS slot selectors ----
    // pA (block0): quads 0,1,2 -> own row (slot w+1) at x+{0,-1,+1}; quad3 -> y-1 (slot w)
    // pB (block1): quad0 -> y+1 (w+2); quad1 -> z-1 (6+w); quad2 -> z+1 (11+w); quad3 pad -> w+2
    const int dxA   = (quad == 1) ? -1 : (quad == 2) ? 1 : 0;
    const int slotA = (quad == 3) ? wave : wave + 1;
    const int slotB = (quad == 1) ? 6 + wave : (quad == 2) ? 11 + wave : wave + 2;
    const int baseA = slotA * SLOT_STRIDE;
    const int baseB = slotB * SLOT_STRIDE;

    const int outrow = z * 16384 + (y0 + wave) * 128;

#pragma unroll
    for (int i = 0; i < 8; ++i) {
        const int X  = i << 4;
        const int xA = (X + col + dxA) & 127;
        bf16x8 s0f = *(const bf16x8*)(lds + baseA + xA * 16);
        bf16x8 s1f = *(const bf16x8*)(lds + baseB + (X + col) * 16);

        // GEMM1: D1[hidden][cell], bias in C
        f32x4 acc = F.b1v;
        acc = __builtin_amdgcn_mfma_f32_16x16x32_bf16(F.w1h0, s0f, acc, 0, 0, 0);
        acc = __builtin_amdgcn_mfma_f32_16x16x32_bf16(F.w1l0, s0f, acc, 0, 0, 0);
        acc = __builtin_amdgcn_mfma_f32_16x16x32_bf16(F.w1h1, s1f, acc, 0, 0, 0);
        acc = __builtin_amdgcn_mfma_f32_16x16x32_bf16(F.w1l1, s1f, acc, 0, 0, 0);

        // tanh
        float h0t, h1t, h2t, h3t;
        {
            float e;
            e = __expf(2.0f * acc[0]); h0t = 1.0f - 2.0f * __builtin_amdgcn_rcpf(e + 1.0f);
            e = __expf(2.0f * acc[1]); h1t = 1.0f - 2.0f * __builtin_amdgcn_rcpf(e + 1.0f);
            e = __expf(2.0f * acc[2]); h2t = 1.0f - 2.0f * __builtin_amdgcn_rcpf(e + 1.0f);
            e = __expf(2.0f * acc[3]); h3t = 1.0f - 2.0f * __builtin_amdgcn_rcpf(e + 1.0f);
        }
        union { bf16x8 v; unsigned int u[4]; } hf;
        hf.u[0] = pack_bf16_rne(h0t, h1t);
        hf.u[1] = pack_bf16_rne(h2t, h3t);
        hf.u[2] = 0u;
        hf.u[3] = 0u;

        // GEMM2: D2[s][cell], bias in C
        f32x4 acc2 = F.b2v;
        acc2 = __builtin_amdgcn_mfma_f32_16x16x32_bf16(F.w2h, hf.v, acc2, 0, 0, 0);
        acc2 = __builtin_amdgcn_mfma_f32_16x16x32_bf16(F.w2l, hf.v, acc2, 0, 0, 0);

        // store: lanes 0..31 contiguous 512 B; nontemporal (out never re-read)
        if (quad < 2) {
            f32x4* p = (f32x4*)(out + (size_t)(outrow + X + col) * 8 + quad * 4);
            __builtin_nontemporal_store(acc2, p);
        }
    }
}

extern "C" void kernel_launch(void* const* d_in, const int* in_sizes, int n_in,
                              void* d_out, int out_size, void* d_ws, size_t ws_size,
                              hipStream_t stream) {
    const float* states = (const float*)d_in[0];
    const float* W1     = (const float*)d_in[1];
    const float* b1     = (const float*)d_in[2];
    const float* W2     = (const float*)d_in[3];
    const float* b2     = (const float*)d_in[4];
    float* out          = (float*)d_out;

    const bool use_ws = ws_size >= (size_t)(8 * 64 * 16);
    if (use_ws) {
        hipLaunchKernelGGL(setup_kernel, dim3(1), dim3(64), 0, stream,
                           W1, b1, W2, b2, (u32x4*)d_ws);
        hipLaunchKernelGGL((lattice_kernel<true>), dim3(4096), dim3(256), 0, stream,
                           states, W1, b1, W2, b2, out, (const u32x4*)d_ws);
    } else {
        hipLaunchKernelGGL((lattice_kernel<false>), dim3(4096), dim3(256), 0, stream,
                           states, W1, b1, W2, b2, out, (const u32x4*)d_ws);
    }
}

// Round 7
// 117.942 us; speedup vs baseline: 1.1471x; 1.1471x over previous
//
#include <hip/hip_runtime.h>

#define DIM 128
#define SLOT_STRIDE 2096   // 131*16: 130 halo cells + pad; 12-bank rotation/slot

typedef __attribute__((ext_vector_type(8))) short bf16x8;
typedef __attribute__((ext_vector_type(4))) float f32x4;
typedef __attribute__((ext_vector_type(4))) unsigned int u32x4;

static __device__ __forceinline__ unsigned short f2bf_rne(float f) {
    union { float f; unsigned int i; } c; c.f = f;
    unsigned int u = c.i;
    return (unsigned short)((u + 0x7fffu + ((u >> 16) & 1u)) >> 16);
}
static __device__ __forceinline__ unsigned int fbits(float f) {
    union { float f; unsigned int i; } c; c.f = f; return c.i;
}
static __device__ __forceinline__ unsigned int pack_bf16_rne(float lo, float hi) {
    unsigned int ul = fbits(lo), uh = fbits(hi);
    unsigned int tl = ul + 0x7fffu + ((ul >> 16) & 1u);
    unsigned int th = uh + 0x7fffu + ((uh >> 16) & 1u);
    return __builtin_amdgcn_perm(th, tl, 0x07060302u);
}

struct Frags {
    bf16x8 w1h0, w1h1, w2h;
    f32x4 b1v, b2v;
};

// GEMM1: A = W1^T (bf16 RNE). W1 k-row order: [own | x-1 | x+1 | y-1 | y+1 | z-1 | z+1]
// -> block0 quads {own,x-1,x+1,y-1}, block1 {y+1,z-1,z+1,pad(0)}.
// GEMM2: A2[m=s][k=8q+j] = (j<4) ? W2[4q+j][s] : 0.
static __device__ __forceinline__ void build_frags(
    const float* W1, const float* b1, const float* W2, const float* b2,
    int col, int quad, Frags& F)
{
#pragma unroll
    for (int j = 0; j < 8; ++j) {
        int k0 = quad * 8 + j;
        F.w1h0[j] = (short)f2bf_rne(W1[k0 * 16 + col]);
        int k1 = 32 + quad * 8 + j;
        F.w1h1[j] = (short)f2bf_rne((k1 < 56) ? W1[k1 * 16 + col] : 0.0f);
        float w2 = (j < 4 && col < 8) ? W2[(quad * 4 + j) * 8 + col] : 0.0f;
        F.w2h[j] = (short)f2bf_rne(w2);
    }
#pragma unroll
    for (int r = 0; r < 4; ++r) {
        F.b1v[r] = b1[quad * 4 + r];
        F.b2v[r] = (quad < 2) ? b2[quad * 4 + r] : 0.0f;
    }
}

__global__ __launch_bounds__(64) void setup_kernel(
    const float* __restrict__ W1, const float* __restrict__ b1,
    const float* __restrict__ W2, const float* __restrict__ b2,
    u32x4* __restrict__ ws)
{
    const int lane = threadIdx.x;
    Frags F;
    build_frags(W1, b1, W2, b2, lane & 15, lane >> 4, F);
    union { bf16x8 v; u32x4 u; } c;
    c.v = F.w1h0; ws[0 * 64 + lane] = c.u;
    c.v = F.w1h1; ws[1 * 64 + lane] = c.u;
    c.v = F.w2h;  ws[2 * 64 + lane] = c.u;
    union { f32x4 v; u32x4 u; } b;
    b.v = F.b1v; ws[3 * 64 + lane] = b.u;
    b.v = F.b2v; ws[4 * 64 + lane] = b.u;
}

// Block (4 waves) covers x=0..127, y=y0..y0+3, one z.
// LDS slots (130 cells each, halo x=-1 and x=128): 0..5 = (y0-1..y0+4, z);
// 6..9 = (y0..y0+3, z-1); 11..14 = (y0..y0+3, z+1); slot 10 = hole.
// Stage: 28 (slot,half) tasks, 7/wave; task geometry wave-uniform (SALU).
template<bool USE_WS>
__global__ __launch_bounds__(256, 5) void lattice_kernel(
    const float* __restrict__ states,
    const float* __restrict__ W1, const float* __restrict__ b1,
    const float* __restrict__ W2, const float* __restrict__ b2,
    float* __restrict__ out, const u32x4* __restrict__ ws)
{
    __shared__ __align__(16) unsigned char lds[15 * SLOT_STRIDE];   // 31440 B

    const int tid  = threadIdx.x;
    const int lane = tid & 63;
    const int w    = __builtin_amdgcn_readfirstlane(tid >> 6);   // wave id, SGPR
    const int col  = lane & 15;
    const int quad = lane >> 4;

    Frags F;
    if (USE_WS) {
        union { u32x4 u; bf16x8 v; } c;
        c.u = ws[0 * 64 + lane]; F.w1h0 = c.v;
        c.u = ws[1 * 64 + lane]; F.w1h1 = c.v;
        c.u = ws[2 * 64 + lane]; F.w2h  = c.v;
        union { u32x4 u; f32x4 v; } b;
        b.u = ws[3 * 64 + lane]; F.b1v = b.v;
        b.u = ws[4 * 64 + lane]; F.b2v = b.v;
    } else {
        build_frags(W1, b1, W2, b2, col, quad, F);
    }

    // z-slab XCD swizzle: blockIdx&7 -> 16-z-plane slab
    const int bI   = blockIdx.x;
    const int slab = bI & 7;
    const int inr  = bI >> 3;            // 0..511
    const int z    = slab * 16 + (inr >> 5);
    const int y0   = (inr & 31) << 2;

    // ---- stage: all loads issued first, then perms + LDS writes ----
    f32x4 ga[7], gb[7];
#pragma unroll
    for (int i = 0; i < 7; ++i) {
        const int tk   = w * 7 + i;                       // SALU
        const int slot = (tk < 20) ? (tk >> 1) : 11 + ((tk - 20) >> 1);
        const int half = tk & 1;
        int yr, zr;
        if (slot < 6)       { yr = (y0 - 1 + slot) & 127; zr = z; }
        else if (slot < 10) { yr = y0 + (slot - 6);       zr = (z - 1) & 127; }
        else                { yr = y0 + (slot - 11);      zr = (z + 1) & 127; }
        const float* g = states + ((size_t)(zr * 16384 + yr * 128 + half * 64) << 3);
        ga[i] = *(const f32x4*)(g + (lane << 3));
        gb[i] = *(const f32x4*)(g + (lane << 3) + 4);
    }
#pragma unroll
    for (int i = 0; i < 7; ++i) {
        const int tk   = w * 7 + i;
        const int slot = (tk < 20) ? (tk >> 1) : 11 + ((tk - 20) >> 1);
        const int half = tk & 1;
        u32x4 p;
        p[0] = __builtin_amdgcn_perm(fbits(ga[i][1]), fbits(ga[i][0]), 0x07060302u);
        p[1] = __builtin_amdgcn_perm(fbits(ga[i][3]), fbits(ga[i][2]), 0x07060302u);
        p[2] = __builtin_amdgcn_perm(fbits(gb[i][1]), fbits(gb[i][0]), 0x07060302u);
        p[3] = __builtin_amdgcn_perm(fbits(gb[i][3]), fbits(gb[i][2]), 0x07060302u);
        const int base = slot * SLOT_STRIDE;
        *(u32x4*)(lds + base + ((half * 64 + lane + 1) << 4)) = p;
        // halo: cell 128 <- cell 0 (half0 lane0); cell -1 <- cell 127 (half1 lane63)
        if (half == 0 && lane == 0)  *(u32x4*)(lds + base + 2064) = p;
        if (half == 1 && lane == 63) *(u32x4*)(lds + base) = p;
    }
    __syncthreads();

    // ---- per-lane LDS base pointers (halo -> no x-wrap, offsets are immediates) ----
    const int dxA   = (quad == 1) ? -1 : (quad == 2) ? 1 : 0;
    const int slotA = (quad == 3) ? w : w + 1;
    const int slotB = (quad == 1) ? 6 + w : (quad == 2) ? 11 + w : w + 2;
    const unsigned char* pA = lds + slotA * SLOT_STRIDE + ((col + dxA + 1) << 4);
    const unsigned char* pB = lds + slotB * SLOT_STRIDE + ((col + 1) << 4);

    float* pO = out + (size_t)((z * 16384 + (y0 + w) * 128 + col) * 8 + quad * 4);

#pragma unroll
    for (int i = 0; i < 8; ++i) {
        bf16x8 s0f = *(const bf16x8*)(pA + (i << 8));
        bf16x8 s1f = *(const bf16x8*)(pB + (i << 8));

        // GEMM1: D1[hidden][cell], bias in C
        f32x4 acc = F.b1v;
        acc = __builtin_amdgcn_mfma_f32_16x16x32_bf16(F.w1h0, s0f, acc, 0, 0, 0);
        acc = __builtin_amdgcn_mfma_f32_16x16x32_bf16(F.w1h1, s1f, acc, 0, 0, 0);

        // tanh
        float h0t, h1t, h2t, h3t;
        {
            float e;
            e = __expf(2.0f * acc[0]); h0t = 1.0f - 2.0f * __builtin_amdgcn_rcpf(e + 1.0f);
            e = __expf(2.0f * acc[1]); h1t = 1.0f - 2.0f * __builtin_amdgcn_rcpf(e + 1.0f);
            e = __expf(2.0f * acc[2]); h2t = 1.0f - 2.0f * __builtin_amdgcn_rcpf(e + 1.0f);
            e = __expf(2.0f * acc[3]); h3t = 1.0f - 2.0f * __builtin_amdgcn_rcpf(e + 1.0f);
        }
        union { bf16x8 v; unsigned int u[4]; } hf;
        hf.u[0] = pack_bf16_rne(h0t, h1t);
        hf.u[1] = pack_bf16_rne(h2t, h3t);
        hf.u[2] = 0u;
        hf.u[3] = 0u;

        // GEMM2: D2[s][cell], bias in C
        f32x4 acc2 = F.b2v;
        acc2 = __builtin_amdgcn_mfma_f32_16x16x32_bf16(F.w2h, hf.v, acc2, 0, 0, 0);

        // store: lanes 0..31 contiguous 512 B; nontemporal (out never re-read)
        if (quad < 2) {
            __builtin_nontemporal_store(acc2, (f32x4*)(pO + (i << 7)));
        }
    }
}

extern "C" void kernel_launch(void* const* d_in, const int* in_sizes, int n_in,
                              void* d_out, int out_size, void* d_ws, size_t ws_size,
                              hipStream_t stream) {
    const float* states = (const float*)d_in[0];
    const float* W1     = (const float*)d_in[1];
    const float* b1     = (const float*)d_in[2];
    const float* W2     = (const float*)d_in[3];
    const float* b2     = (const float*)d_in[4];
    float* out          = (float*)d_out;

    const bool use_ws = ws_size >= (size_t)(5 * 64 * 16);
    if (use_ws) {
        hipLaunchKernelGGL(setup_kernel, dim3(1), dim3(64), 0, stream,
                           W1, b1, W2, b2, (u32x4*)d_ws);
        hipLaunchKernelGGL((lattice_kernel<true>), dim3(4096), dim3(256), 0, stream,
                           states, W1, b1, W2, b2, out, (const u32x4*)d_ws);
    } else {
        hipLaunchKernelGGL((lattice_kernel<false>), dim3(4096), dim3(256), 0, stream,
                           states, W1, b1, W2, b2, out, (const u32x4*)d_ws);
    }
}